// Round 3
// baseline (1371.231 us; speedup 1.0000x reference)
//
#include <hip/hip_runtime.h>
#include <hip/hip_bf16.h>
#include <math.h>

#define V 65536
#define G 2048
#define NPG 32
#define DEG 4
#define NE (V*DEG)
#define H 200
#define NODE_IN 74
#define EDGE_IN 12
#define NL 5

#define KP 224      // GEMM K padded (7 x 32)
#define NP 208      // feature dim padded (13 x 16)
#define AR32 228    // aggplane row stride in u32 (912 B; 228%32=4 -> 2-way banks, free)
#define EK 32       // edge-mfma K

typedef __attribute__((ext_vector_type(8))) short short8;
typedef __attribute__((ext_vector_type(4))) float floatx4;

__device__ __forceinline__ float sigmoidf_(float x) { return 1.f / (1.f + __expf(-x)); }

__device__ __forceinline__ unsigned f2bf_bits(float f) {
    unsigned u = __float_as_uint(f);
    return (u + 0x7fffu + ((u >> 16) & 1u)) >> 16;  // RNE
}
__device__ __forceinline__ float bf2f(unsigned bits) { return __uint_as_float(bits << 16); }

// ---------------- node embedding: h = node_feat @ node_W + node_b ----------------
__global__ __launch_bounds__(256) void k_node_embed(const float* __restrict__ nf,
                                                    const float* __restrict__ W,
                                                    const float* __restrict__ b,
                                                    float* __restrict__ h) {
    __shared__ float fs[16][NODE_IN];
    const int tid = threadIdx.x;
    const int base = blockIdx.x * 16;
    for (int p = tid; p < 16 * NODE_IN; p += 256) {
        int n = p / NODE_IN, i = p - n * NODE_IN;
        fs[n][i] = nf[(base + n) * NODE_IN + i];
    }
    __syncthreads();
    const int j = tid;
    if (j < H) {
        float acc[16];
#pragma unroll
        for (int n = 0; n < 16; n++) acc[n] = 0.f;
        for (int i = 0; i < NODE_IN; i++) {
            float w = W[i * H + j];
#pragma unroll
            for (int n = 0; n < 16; n++) acc[n] = fmaf(fs[n][i], w, acc[n]);
        }
        float bj = b[j];
        for (int n = 0; n < 16; n++) h[(base + n) * H + j] = acc[n] + bj;
    }
}

// ---------------- prep: gnn_W -> transposed hi/lo bf16 planes [NL][NP][KP] ----------------
__global__ __launch_bounds__(256) void k_prep_w(const float* __restrict__ gnnW,
                                                unsigned short* __restrict__ WtHi,
                                                unsigned short* __restrict__ WtLo) {
    int idx = blockIdx.x * 256 + threadIdx.x;
    if (idx >= NL * NP * KP) return;
    int l = idx / (NP * KP);
    int rem = idx - l * NP * KP;
    int n = rem / KP;
    int k = rem - n * KP;
    float w = (n < H && k < H) ? gnnW[l * H * H + k * H + n] : 0.f;
    unsigned hb = f2bf_bits(w);
    unsigned lb = f2bf_bits(w - bf2f(hb));
    WtHi[idx] = (unsigned short)hb;
    WtLo[idx] = (unsigned short)lb;
}

// ---------------- prep: edge_W/edge_b -> B planes for edge MFMA [NP][64] bf16 ----------------
// row j: cols 0..31 = B1 (k0..11=whi, k12..23=whi, k24=eb_hi, k25=eb_lo, rest 0)
//        cols 32..63 = B2 (k0..11=wlo, rest 0)
__global__ __launch_bounds__(256) void k_prep_ew(const float* __restrict__ eW,
                                                 const float* __restrict__ eb,
                                                 unsigned short* __restrict__ eWp) {
    int t = threadIdx.x;
    if (t >= NP) return;
    unsigned short row[64];
    for (int i = 0; i < 64; i++) row[i] = 0;
    if (t < H) {
        for (int k = 0; k < EDGE_IN; k++) {
            float w = eW[k * H + t];
            unsigned hb = f2bf_bits(w);
            unsigned lb = f2bf_bits(w - bf2f(hb));
            row[k] = (unsigned short)hb;
            row[12 + k] = (unsigned short)hb;
            row[32 + k] = (unsigned short)lb;
        }
        float e = eb[t];
        unsigned ebh = f2bf_bits(e);
        unsigned ebl = f2bf_bits(e - bf2f(ebh));
        row[24] = (unsigned short)ebh;
        row[25] = (unsigned short)ebl;
    }
    for (int i = 0; i < 64; i++) eWp[t * 64 + i] = row[i];
}

// ---------------- prep: ef -> edge A-plane [NE][EK] bf16: [hi12 | lo12 | 1,1 | 0...] ----------------
__global__ __launch_bounds__(256) void k_prep_ef(const float* __restrict__ ef,
                                                 unsigned short* __restrict__ Aedge) {
    __shared__ float efs[256 * EDGE_IN];
    const int tid = threadIdx.x, blk = blockIdx.x;
    const float4* gs = (const float4*)(ef + (size_t)blk * 256 * EDGE_IN);
    float4* ds = (float4*)efs;
    for (int p = tid; p < 256 * EDGE_IN / 4; p += 256) ds[p] = gs[p];
    __syncthreads();
    unsigned hb[EDGE_IN], lb[EDGE_IN];
    for (int k = 0; k < EDGE_IN; k++) {
        float v = efs[tid * EDGE_IN + k];
        hb[k] = f2bf_bits(v);
        lb[k] = f2bf_bits(v - bf2f(hb[k]));
    }
    unsigned w[16];
    for (int i = 0; i < 6; i++) w[i] = hb[2 * i] | (hb[2 * i + 1] << 16);
    for (int i = 0; i < 6; i++) w[6 + i] = lb[2 * i] | (lb[2 * i + 1] << 16);
    w[12] = 0x3F803F80u;  // bf16(1.0) x2
    w[13] = 0u; w[14] = 0u; w[15] = 0u;
    uint4* dst = (uint4*)(Aedge + ((size_t)blk * 256 + tid) * EK);
    dst[0] = make_uint4(w[0], w[1], w[2], w[3]);
    dst[1] = make_uint4(w[4], w[5], w[6], w[7]);
    dst[2] = make_uint4(w[8], w[9], w[10], w[11]);
    dst[3] = make_uint4(w[12], w[13], w[14], w[15]);
}

// ---------------- K1: per-graph edge-softmax aggregation (edge embed via MFMA) ----------------
// Writes aggplane [V][AR32] u32: per row, chunk c (k=8c..8c+7): hi8 bf16 @ byte c*32, lo8 @ c*32+16.
__global__ __launch_bounds__(256) void k1_agg(const float* __restrict__ h,
                                              const unsigned short* __restrict__ Aedge,
                                              const unsigned short* __restrict__ eWp,
                                              const int* __restrict__ src,
                                              unsigned int* __restrict__ aggp) {
    __shared__ alignas(16) float h_s[NPG * H];
    __shared__ int src_s[NPG * DEG];
    const int g = blockIdx.x, tid = threadIdx.x;
    const int nbase = g * NPG;

    const float4* hsrc = (const float4*)(h + (size_t)nbase * H);
    float4* hdst = (float4*)h_s;
    for (int p = tid; p < NPG * H / 4; p += 256) hdst[p] = hsrc[p];
    if (tid < NPG * DEG) src_s[tid] = src[g * NPG * DEG + tid] - nbase;
    // zero k=208..223 region (u32 cols 208..223)
    for (int p = tid; p < NPG * 16; p += 256) {
        int row = p >> 4, wd = p & 15;
        aggp[(size_t)(nbase + row) * AR32 + 208 + wd] = 0u;
    }
    __syncthreads();

    const int wave = tid >> 6, lane = tid & 63;
    const int l15 = lane & 15, quad = lane >> 4;

    // preload 8 edge A-fragments (all 128 edges of the graph)
    short8 af[8];
    const unsigned short* abase = Aedge + (size_t)g * NPG * DEG * EK;
#pragma unroll
    for (int mt = 0; mt < 8; mt++)
        af[mt] = *(const short8*)&abase[(16 * mt + l15) * EK + quad * 8];

    const int ntcnt = (wave == 0) ? 4 : 3;
    for (int i = 0; i < ntcnt; i++) {
        const int nt = wave + 4 * i;
        const int jj = nt * 16 + l15;
        short8 b1 = *(const short8*)&eWp[(size_t)(nt * 16 + l15) * 64 + quad * 8];
        short8 b2 = *(const short8*)&eWp[(size_t)(nt * 16 + l15) * 64 + 32 + quad * 8];
        floatx4 fr[8];
#pragma unroll
        for (int mt = 0; mt < 8; mt++) {
            floatx4 z = {0.f, 0.f, 0.f, 0.f};
            z = __builtin_amdgcn_mfma_f32_16x16x32_bf16(af[mt], b1, z, 0, 0, 0);
            z = __builtin_amdgcn_mfma_f32_16x16x32_bf16(af[mt], b2, z, 0, 0, 0);
            fr[mt] = z;  // lane holds eh for node 4*mt+quad, its 4 edges, feature jj
        }
        const int jc = jj < H ? jj : H - 1;
        for (int mt = 0; mt < 8; mt++) {
            const int node = 4 * mt + quad;
            float m0 = fr[mt][0] + h_s[src_s[node * 4 + 0] * H + jc];
            float m1 = fr[mt][1] + h_s[src_s[node * 4 + 1] * H + jc];
            float m2 = fr[mt][2] + h_s[src_s[node * 4 + 2] * H + jc];
            float m3 = fr[mt][3] + h_s[src_s[node * 4 + 3] * H + jc];
            float mx = fmaxf(fmaxf(m0, m1), fmaxf(m2, m3));
            float e0 = __expf(m0 - mx), e1 = __expf(m1 - mx);
            float e2 = __expf(m2 - mx), e3 = __expf(m3 - mx);
            float den = e0 + e1 + e2 + e3;
            float num = fmaf(m0, e0, fmaf(m1, e1, fmaf(m2, e2, m3 * e3)));
            float agg = __fdividef(num, den);
            if (jj >= H) agg = 0.f;
            unsigned hbb = f2bf_bits(agg);
            unsigned lbb = f2bf_bits(agg - bf2f(hbb));
            unsigned short* rowp = (unsigned short*)(aggp + (size_t)(nbase + node) * AR32);
            int c = jj >> 3, o = jj & 7;
            rowp[c * 16 + o] = (unsigned short)hbb;
            rowp[c * 16 + 8 + o] = (unsigned short)lbb;
        }
    }
}

// ---------------- K2: h = relu(agg @ W + b) + h  (dense GEMM, split-3 bf16, in-place) ----------------
__global__ __launch_bounds__(256) void k2_gemm(const unsigned int* __restrict__ aggp,
                                               const unsigned short* __restrict__ WtHi,
                                               const unsigned short* __restrict__ WtLo,
                                               const float* __restrict__ b,
                                               float* __restrict__ h) {
    __shared__ alignas(16) unsigned int a_s[64 * AR32];  // 58368 B
    const int blk = blockIdx.x, tid = threadIdx.x;
    const int rowbase = blk * 64;

    const uint4* gs = (const uint4*)(aggp + (size_t)rowbase * AR32);
    uint4* ds = (uint4*)a_s;
    for (int p = tid; p < 64 * AR32 / 4; p += 256) ds[p] = gs[p];
    __syncthreads();

    const int wave = tid >> 6, lane = tid & 63;
    const int l15 = lane & 15, quad = lane >> 4;
    const int ntcnt = (wave == 0) ? 4 : 3;

    floatx4 acc[4][4];
#pragma unroll
    for (int mt = 0; mt < 4; mt++)
#pragma unroll
        for (int i = 0; i < 4; i++) acc[mt][i] = (floatx4){0.f, 0.f, 0.f, 0.f};

    for (int ks = 0; ks < KP / 32; ks++) {
        short8 ah[4], al[4];
#pragma unroll
        for (int mt = 0; mt < 4; mt++) {
            int off = (16 * mt + l15) * AR32 + (4 * ks + quad) * 8;
            ah[mt] = *(const short8*)&a_s[off];
            al[mt] = *(const short8*)&a_s[off + 4];
        }
#pragma unroll 4
        for (int i = 0; i < ntcnt; i++) {
            int nt = wave + 4 * i;
            size_t boff = (size_t)(16 * nt + l15) * KP + ks * 32 + quad * 8;
            short8 vbh = *(const short8*)&WtHi[boff];
            short8 vbl = *(const short8*)&WtLo[boff];
#pragma unroll
            for (int mt = 0; mt < 4; mt++) {
                acc[mt][i] = __builtin_amdgcn_mfma_f32_16x16x32_bf16(ah[mt], vbh, acc[mt][i], 0, 0, 0);
                acc[mt][i] = __builtin_amdgcn_mfma_f32_16x16x32_bf16(al[mt], vbh, acc[mt][i], 0, 0, 0);
                acc[mt][i] = __builtin_amdgcn_mfma_f32_16x16x32_bf16(ah[mt], vbl, acc[mt][i], 0, 0, 0);
            }
        }
    }

    for (int i = 0; i < ntcnt; i++) {
        int nt = wave + 4 * i, jj = nt * 16 + l15;
        if (jj < H) {
            float bj = b[jj];
#pragma unroll
            for (int mt = 0; mt < 4; mt++) {
#pragma unroll
                for (int r = 0; r < 4; r++) {
                    int node = rowbase + 16 * mt + quad * 4 + r;
                    float v = acc[mt][i][r] + bj;
                    v = v > 0.f ? v : 0.f;
                    h[(size_t)node * H + jj] += v;  // residual, in-place
                }
            }
        }
    }
}

// ---------------- gf init ----------------
__global__ __launch_bounds__(256) void k_gf_init(const float* __restrict__ h, float* __restrict__ gf) {
    const int g = blockIdx.x, j = threadIdx.x;
    if (j < H) {
        float s = 0.f;
        for (int n = 0; n < NPG; n++) s += h[(g * NPG + n) * H + j];
        gf[g * H + j] = s;
    }
}

// ---------------- readout attention ----------------
__global__ __launch_bounds__(256) void k_attn(const float* __restrict__ h,
                                              const float* __restrict__ gf,
                                              const float* __restrict__ lgW,
                                              const float* __restrict__ lgb,
                                              const float* __restrict__ prW,
                                              const float* __restrict__ prb,
                                              float* __restrict__ ctx_out) {
    __shared__ float h_s[NPG][H];
    __shared__ float gf_s[H];
    __shared__ float zp[256];
    __shared__ float z_s[NPG];
    __shared__ float a_s[NPG];
    __shared__ float wh_s[H];
    const int g = blockIdx.x, tid = threadIdx.x;

    for (int p = tid; p < NPG * H; p += 256) h_s[0][p] = h[g * NPG * H + p];
    if (tid < H) gf_s[tid] = gf[g * H + tid];
    __syncthreads();

    float c = 0.f;
    for (int jj = 0; jj < H; jj++) c = fmaf(fmaxf(gf_s[jj], 0.f), lgW[jj], c);

    {
        const int n = tid >> 3, l = tid & 7;
        float p = 0.f;
        for (int jj = l; jj < H; jj += 8) p = fmaf(h_s[n][jj], lgW[H + jj], p);
        zp[tid] = p;
    }
    __syncthreads();
    if (tid < NPG) {
        float z = c + lgb[0];
        for (int q = 0; q < 8; q++) z += zp[tid * 8 + q];
        z_s[tid] = z > 0.f ? z : 0.01f * z;
    }
    __syncthreads();
    float zmax = -1e30f;
    for (int n = 0; n < NPG; n++) zmax = fmaxf(zmax, z_s[n]);
    if (tid < NPG) a_s[tid] = __expf(z_s[tid] - zmax);
    __syncthreads();
    float den = 0.f;
    for (int n = 0; n < NPG; n++) den += a_s[n];

    if (tid < H) {
        float s = 0.f;
        for (int n = 0; n < NPG; n++) s = fmaf(a_s[n], h_s[n][tid], s);
        wh_s[tid] = s / den;
    }
    __syncthreads();

    if (tid < H) {
        float s = prb[tid];
        for (int i = 0; i < H; i++) s = fmaf(wh_s[i], prW[i * H + tid], s);
        ctx_out[g * H + tid] = s > 0.f ? s : __expf(s) - 1.f;
    }
}

// ---------------- GRU cell ----------------
#define GPB 8
#define GP 9
__global__ __launch_bounds__(256) void k_gru(const float* __restrict__ ctx,
                                             const float* __restrict__ gf,
                                             const float* __restrict__ Wih,
                                             const float* __restrict__ Whh,
                                             const float* __restrict__ bih,
                                             const float* __restrict__ bhh,
                                             float* __restrict__ gf_out) {
    __shared__ float ctx_s[GPB][H];
    __shared__ float gfs[GPB][H];
    __shared__ float gi_s[3 * H][GP];
    __shared__ float gh_s[3 * H][GP];
    const int gbase = blockIdx.x * GPB, tid = threadIdx.x;

    for (int p = tid; p < GPB * H; p += 256) {
        ctx_s[0][p] = ctx[gbase * H + p];
        gfs[0][p] = gf[gbase * H + p];
    }
    __syncthreads();

    for (int k = tid; k < 3 * H; k += 256) {
        float ai[GPB], ah[GPB];
        float bi = bih[k], bh = bhh[k];
#pragma unroll
        for (int q = 0; q < GPB; q++) { ai[q] = bi; ah[q] = bh; }
        for (int jj = 0; jj < H; jj++) {
            float wi = Wih[k * H + jj];
            float wh = Whh[k * H + jj];
#pragma unroll
            for (int q = 0; q < GPB; q++) {
                ai[q] = fmaf(ctx_s[q][jj], wi, ai[q]);
                ah[q] = fmaf(gfs[q][jj], wh, ah[q]);
            }
        }
#pragma unroll
        for (int q = 0; q < GPB; q++) { gi_s[k][q] = ai[q]; gh_s[k][q] = ah[q]; }
    }
    __syncthreads();

    for (int p = tid; p < GPB * H; p += 256) {
        int q = p / H, jj = p - q * H;
        float r = sigmoidf_(gi_s[jj][q] + gh_s[jj][q]);
        float u = sigmoidf_(gi_s[H + jj][q] + gh_s[H + jj][q]);
        float nn = tanhf(gi_s[2 * H + jj][q] + r * gh_s[2 * H + jj][q]);
        gf_out[(gbase + q) * H + jj] = (1.f - u) * nn + u * gfs[q][jj];
    }
}

extern "C" void kernel_launch(void* const* d_in, const int* in_sizes, int n_in,
                              void* d_out, int out_size, void* d_ws, size_t ws_size,
                              hipStream_t stream) {
    const float* node_feat = (const float*)d_in[0];
    const float* edge_feat = (const float*)d_in[1];
    const int* src = (const int*)d_in[2];
    const float* node_W = (const float*)d_in[5];
    const float* node_b = (const float*)d_in[6];
    const float* edge_W = (const float*)d_in[7];
    const float* edge_b = (const float*)d_in[8];
    const float* gnn_W = (const float*)d_in[9];
    const float* gnn_b = (const float*)d_in[10];
    const float* lg_W = (const float*)d_in[11];
    const float* lg_b = (const float*)d_in[12];
    const float* pr_W = (const float*)d_in[13];
    const float* pr_b = (const float*)d_in[14];
    const float* W_ih = (const float*)d_in[15];
    const float* W_hh = (const float*)d_in[16];
    const float* b_ih = (const float*)d_in[17];
    const float* b_hh = (const float*)d_in[18];
    float* out = (float*)d_out;

    char* ws = (char*)d_ws;
    size_t off = 0;
    auto alloc = [&](size_t bytes) { void* p = ws + off; off += (bytes + 4095) & ~(size_t)4095; return p; };
    float* h = (float*)alloc((size_t)V * H * 4);
    unsigned int* aggp = (unsigned int*)alloc((size_t)V * AR32 * 4);
    unsigned short* Aedge = (unsigned short*)alloc((size_t)NE * EK * 2);
    unsigned short* WtHi = (unsigned short*)alloc((size_t)NL * NP * KP * 2);
    unsigned short* WtLo = (unsigned short*)alloc((size_t)NL * NP * KP * 2);
    unsigned short* eWp = (unsigned short*)alloc((size_t)NP * 64 * 2);
    float* gf_ws = (float*)alloc((size_t)G * H * 4);
    float* ctx_ws = (float*)alloc((size_t)G * H * 4);

    k_prep_w<<<(NL * NP * KP + 255) / 256, 256, 0, stream>>>(gnn_W, WtHi, WtLo);
    k_prep_ew<<<1, 256, 0, stream>>>(edge_W, edge_b, eWp);
    k_prep_ef<<<NE / 256, 256, 0, stream>>>(edge_feat, Aedge);
    k_node_embed<<<V / 16, 256, 0, stream>>>(node_feat, node_W, node_b, h);

    for (int l = 0; l < NL; l++) {
        k1_agg<<<G, 256, 0, stream>>>(h, Aedge, eWp, src, aggp);
        k2_gemm<<<V / 64, 256, 0, stream>>>(aggp, WtHi + (size_t)l * NP * KP,
                                            WtLo + (size_t)l * NP * KP, gnn_b + (size_t)l * H, h);
    }

    k_gf_init<<<G, 256, 0, stream>>>(h, gf_ws);
    for (int t = 0; t < 2; t++) {
        k_attn<<<G, 256, 0, stream>>>(h, gf_ws, lg_W + (size_t)t * 2 * H, lg_b + t,
                                      pr_W + (size_t)t * H * H, pr_b + (size_t)t * H, ctx_ws);
        float* gout = (t == 1) ? out : gf_ws;
        k_gru<<<G / GPB, 256, 0, stream>>>(ctx_ws, gf_ws, W_ih + (size_t)t * 3 * H * H,
                                           W_hh + (size_t)t * 3 * H * H, b_ih + (size_t)t * 3 * H,
                                           b_hh + (size_t)t * 3 * H, gout);
    }
}

// Round 4
// 791.850 us; speedup vs baseline: 1.7317x; 1.7317x over previous
//
#include <hip/hip_runtime.h>
#include <hip/hip_bf16.h>
#include <math.h>

#define V 65536
#define G 2048
#define NPG 32
#define DEG 4
#define NE (V*DEG)
#define H 200
#define NODE_IN 74
#define EDGE_IN 12
#define NL 5

#define KP 224      // GEMM K padded (7 x 32)
#define NP 208      // feature dim padded (13 x 16)
#define AR32 228    // agg LDS row stride in u32
#define EK 32       // edge-mfma K
#define HS 200      // h_s row stride (floats)
#define AES 40      // aedge_s row stride (u16), 80 B: 16B-aligned rows, good banks
#define NFS 200     // Anf row stride (u16): [hi 96 | lo 96 | pad 8]

typedef __attribute__((ext_vector_type(8))) short short8;
typedef __attribute__((ext_vector_type(4))) float floatx4;

__device__ __forceinline__ float sigmoidf_(float x) { return 1.f / (1.f + __expf(-x)); }

__device__ __forceinline__ unsigned f2bf_bits(float f) {
    unsigned u = __float_as_uint(f);
    return (u + 0x7fffu + ((u >> 16) & 1u)) >> 16;  // RNE
}
__device__ __forceinline__ float bf2f(unsigned bits) { return __uint_as_float(bits << 16); }
__device__ __forceinline__ unsigned lo_bits(float f, unsigned hb) {
    return f2bf_bits(f - bf2f(hb));
}

// ---------------- prep: gnn_W -> transposed hi/lo bf16 planes [NL][NP][KP] ----------------
__global__ __launch_bounds__(256) void k_prep_w(const float* __restrict__ gnnW,
                                                unsigned short* __restrict__ WtHi,
                                                unsigned short* __restrict__ WtLo) {
    int idx = blockIdx.x * 256 + threadIdx.x;
    if (idx >= NL * NP * KP) return;
    int l = idx / (NP * KP);
    int rem = idx - l * NP * KP;
    int n = rem / KP;
    int k = rem - n * KP;
    float w = (n < H && k < H) ? gnnW[l * H * H + k * H + n] : 0.f;
    unsigned hb = f2bf_bits(w);
    WtHi[idx] = (unsigned short)hb;
    WtLo[idx] = (unsigned short)lo_bits(w, hb);
}

// ---------------- prep: edge_W/edge_b -> B planes [NP][64] ----------------
__global__ __launch_bounds__(256) void k_prep_ew(const float* __restrict__ eW,
                                                 const float* __restrict__ eb,
                                                 unsigned short* __restrict__ eWp) {
    int t = threadIdx.x;
    if (t >= NP) return;
    unsigned short row[64];
    for (int i = 0; i < 64; i++) row[i] = 0;
    if (t < H) {
        for (int k = 0; k < EDGE_IN; k++) {
            float w = eW[k * H + t];
            unsigned hb = f2bf_bits(w);
            row[k] = (unsigned short)hb;
            row[12 + k] = (unsigned short)hb;
            row[32 + k] = (unsigned short)lo_bits(w, hb);
        }
        float e = eb[t];
        unsigned ebh = f2bf_bits(e);
        row[24] = (unsigned short)ebh;
        row[25] = (unsigned short)lo_bits(e, ebh);
    }
    for (int i = 0; i < 64; i++) eWp[t * 64 + i] = row[i];
}

// ---------------- prep: ef -> edge A-plane [NE][EK]: [hi12 | lo12 | 1,1 | 0...] ----------------
__global__ __launch_bounds__(256) void k_prep_ef(const float* __restrict__ ef,
                                                 unsigned short* __restrict__ Aedge) {
    __shared__ float efs[256 * EDGE_IN];
    const int tid = threadIdx.x, blk = blockIdx.x;
    const float4* gs = (const float4*)(ef + (size_t)blk * 256 * EDGE_IN);
    float4* ds = (float4*)efs;
    for (int p = tid; p < 256 * EDGE_IN / 4; p += 256) ds[p] = gs[p];
    __syncthreads();
    unsigned hb[EDGE_IN], lb[EDGE_IN];
    for (int k = 0; k < EDGE_IN; k++) {
        float v = efs[tid * EDGE_IN + k];
        hb[k] = f2bf_bits(v);
        lb[k] = lo_bits(v, hb[k]);
    }
    unsigned w[16];
    for (int i = 0; i < 6; i++) w[i] = hb[2 * i] | (hb[2 * i + 1] << 16);
    for (int i = 0; i < 6; i++) w[6 + i] = lb[2 * i] | (lb[2 * i + 1] << 16);
    w[12] = 0x3F803F80u;  // k24,k25 = 1.0 (bias rows)
    w[13] = 0u; w[14] = 0u; w[15] = 0u;
    uint4* dst = (uint4*)(Aedge + ((size_t)blk * 256 + tid) * EK);
    dst[0] = make_uint4(w[0], w[1], w[2], w[3]);
    dst[1] = make_uint4(w[4], w[5], w[6], w[7]);
    dst[2] = make_uint4(w[8], w[9], w[10], w[11]);
    dst[3] = make_uint4(w[12], w[13], w[14], w[15]);
}

// ---------------- prep: node_feat -> A planes [V][NFS]: [hi74,1,1,0x20 | lo74,0x22 | pad8] ----------------
__global__ __launch_bounds__(256) void k_prep_nf(const float* __restrict__ nf,
                                                 unsigned int* __restrict__ Anf) {
    __shared__ float nf_s[64 * NODE_IN];
    const int tid = threadIdx.x, blk = blockIdx.x;
    const float4* gs = (const float4*)(nf + (size_t)blk * 64 * NODE_IN);
    float4* ds = (float4*)nf_s;
    for (int p = tid; p < 64 * NODE_IN / 4; p += 256) ds[p] = gs[p];
    __syncthreads();
    for (int p = tid; p < 64 * 100; p += 256) {
        int row = p / 100, c = p - row * 100;
        unsigned v0 = 0, v1 = 0;
        if (c < 48) {             // hi plane: k = 2c, 2c+1
            int k0 = 2 * c;
            if (k0 < NODE_IN) v0 = f2bf_bits(nf_s[row * NODE_IN + k0]);
            else if (k0 == 74 || k0 == 75) v0 = 0x3F80u;
            int k1 = k0 + 1;
            if (k1 < NODE_IN) v1 = f2bf_bits(nf_s[row * NODE_IN + k1]);
            else if (k1 == 74 || k1 == 75) v1 = 0x3F80u;
        } else if (c < 96) {      // lo plane: k' = 2(c-48), +1
            int k0 = 2 * (c - 48);
            if (k0 < NODE_IN) { float x = nf_s[row * NODE_IN + k0]; v0 = lo_bits(x, f2bf_bits(x)); }
            int k1 = k0 + 1;
            if (k1 < NODE_IN) { float x = nf_s[row * NODE_IN + k1]; v1 = lo_bits(x, f2bf_bits(x)); }
        }
        Anf[((size_t)blk * 64 + row) * 100 + c] = v0 | (v1 << 16);
    }
}

// ---------------- prep: node_W/node_b -> B planes [NP][192]: [hi74,bhi,blo,0 | lo74,0] ----------------
__global__ __launch_bounds__(256) void k_prep_nw(const float* __restrict__ nW,
                                                 const float* __restrict__ nb,
                                                 unsigned int* __restrict__ BnW) {
    int idx = blockIdx.x * 256 + threadIdx.x;
    if (idx >= NP * 96) return;
    int jj = idx / 96, c = idx - jj * 96;
    unsigned v0 = 0, v1 = 0;
    if (jj < H) {
        if (c < 48) {
            int k0 = 2 * c, k1 = k0 + 1;
            if (k0 < NODE_IN) v0 = f2bf_bits(nW[k0 * H + jj]);
            else if (k0 == 74) v0 = f2bf_bits(nb[jj]);
            else if (k0 == 75) { float b = nb[jj]; v0 = lo_bits(b, f2bf_bits(b)); }
            if (k1 < NODE_IN) v1 = f2bf_bits(nW[k1 * H + jj]);
            else if (k1 == 74) v1 = f2bf_bits(nb[jj]);
            else if (k1 == 75) { float b = nb[jj]; v1 = lo_bits(b, f2bf_bits(b)); }
        } else {
            int k0 = 2 * (c - 48), k1 = k0 + 1;
            if (k0 < NODE_IN) { float x = nW[k0 * H + jj]; v0 = lo_bits(x, f2bf_bits(x)); }
            if (k1 < NODE_IN) { float x = nW[k1 * H + jj]; v1 = lo_bits(x, f2bf_bits(x)); }
        }
    }
    BnW[idx] = v0 | (v1 << 16);
}

// ---------------- MEGA: embed + 5 GNN layers + gf, one block per graph ----------------
__global__ __launch_bounds__(256, 2) void k_mega(const unsigned short* __restrict__ Anf,
                                                 const unsigned short* __restrict__ BnW,
                                                 const unsigned short* __restrict__ Aedge,
                                                 const unsigned short* __restrict__ eWp,
                                                 const int* __restrict__ src,
                                                 const unsigned short* __restrict__ WtHi,
                                                 const unsigned short* __restrict__ WtLo,
                                                 const float* __restrict__ gnn_b,
                                                 float* __restrict__ h_out,
                                                 float* __restrict__ gf_out) {
    __shared__ alignas(16) float h_s[NPG * HS];                  // 25600 B
    __shared__ alignas(16) unsigned int agg[NPG * AR32];         // 29184 B (also Anf staging)
    __shared__ alignas(16) unsigned short aedge_s[NPG * DEG * AES];  // 10240 B
    __shared__ unsigned char src_s[NPG * DEG];                   // 128 B
    const int g = blockIdx.x, tid = threadIdx.x;
    const int nbase = g * NPG, ebase = g * NPG * DEG;

    // stage edge planes (64 B/row -> 80 B-stride rows) + src + Anf (into agg area)
    {
        const uint4* s4 = (const uint4*)(Aedge + (size_t)ebase * EK);
        for (int p = tid; p < NPG * DEG * 4; p += 256) {
            int r = p >> 2, w = p & 3;
            *(uint4*)&aedge_s[r * AES + w * 8] = s4[p];
        }
        if (tid < NPG * DEG) src_s[tid] = (unsigned char)(src[ebase + tid] - nbase);
        const uint4* n4 = (const uint4*)(Anf + (size_t)nbase * NFS);
        uint4* d4 = (uint4*)agg;
        for (int p = tid; p < NPG * NFS * 2 / 16; p += 256) d4[p] = n4[p];
    }
    __syncthreads();

    const int wave = tid >> 6, lane = tid & 63;
    const int l15 = lane & 15, quad = lane >> 4;
    const int ntcnt = (wave == 0) ? 4 : 3;

    // ---- embed: h = nf @ nW + nb (split-3 bf16 MFMA) ----
    {
        const unsigned short* nf_s = (const unsigned short*)agg;
        for (int i = 0; i < ntcnt; i++) {
            int nt = wave + 4 * i, jj = nt * 16 + l15;
            floatx4 acc[2];
            acc[0] = (floatx4){0.f, 0.f, 0.f, 0.f};
            acc[1] = (floatx4){0.f, 0.f, 0.f, 0.f};
            for (int ks = 0; ks < 3; ks++) {
                short8 bh = *(const short8*)&BnW[(size_t)jj * 192 + ks * 32 + quad * 8];
                short8 bl = *(const short8*)&BnW[(size_t)jj * 192 + 96 + ks * 32 + quad * 8];
#pragma unroll
                for (int mt = 0; mt < 2; mt++) {
                    const unsigned short* arow = nf_s + (16 * mt + l15) * NFS;
                    short8 ah = *(const short8*)&arow[ks * 32 + quad * 8];
                    short8 al = *(const short8*)&arow[96 + ks * 32 + quad * 8];
                    acc[mt] = __builtin_amdgcn_mfma_f32_16x16x32_bf16(ah, bh, acc[mt], 0, 0, 0);
                    acc[mt] = __builtin_amdgcn_mfma_f32_16x16x32_bf16(al, bh, acc[mt], 0, 0, 0);
                    acc[mt] = __builtin_amdgcn_mfma_f32_16x16x32_bf16(ah, bl, acc[mt], 0, 0, 0);
                }
            }
            if (jj < H) {
#pragma unroll
                for (int mt = 0; mt < 2; mt++)
#pragma unroll
                    for (int r = 0; r < 4; r++)
                        h_s[(16 * mt + quad * 4 + r) * HS + jj] = acc[mt][r];
            }
        }
    }
    __syncthreads();
    // zero agg K-pad (u32 cols 208..223) once; chunks <=25 rewritten each layer
    for (int p = tid; p < NPG * 16; p += 256) {
        int row = p >> 4, wd = p & 15;
        agg[row * AR32 + 208 + wd] = 0u;
    }

    for (int l = 0; l < NL; l++) {
        // ---- phase 1: edge eh via MFMA + lane-local 4-edge softmax -> agg planes (LDS) ----
        short8 af[8];
#pragma unroll
        for (int mt = 0; mt < 8; mt++)
            af[mt] = *(const short8*)&aedge_s[(16 * mt + l15) * AES + quad * 8];
        for (int i = 0; i < ntcnt; i++) {
            int nt = wave + 4 * i, jj = nt * 16 + l15;
            short8 b1 = *(const short8*)&eWp[(size_t)jj * 64 + quad * 8];
            short8 b2 = *(const short8*)&eWp[(size_t)jj * 64 + 32 + quad * 8];
            int jc = jj < H ? jj : H - 1;
#pragma unroll
            for (int mt = 0; mt < 8; mt++) {
                floatx4 z = (floatx4){0.f, 0.f, 0.f, 0.f};
                z = __builtin_amdgcn_mfma_f32_16x16x32_bf16(af[mt], b1, z, 0, 0, 0);
                z = __builtin_amdgcn_mfma_f32_16x16x32_bf16(af[mt], b2, z, 0, 0, 0);
                const int node = 4 * mt + quad;
                float m0 = z[0] + h_s[src_s[node * 4 + 0] * HS + jc];
                float m1 = z[1] + h_s[src_s[node * 4 + 1] * HS + jc];
                float m2 = z[2] + h_s[src_s[node * 4 + 2] * HS + jc];
                float m3 = z[3] + h_s[src_s[node * 4 + 3] * HS + jc];
                float mx = fmaxf(fmaxf(m0, m1), fmaxf(m2, m3));
                float e0 = __expf(m0 - mx), e1 = __expf(m1 - mx);
                float e2 = __expf(m2 - mx), e3 = __expf(m3 - mx);
                float den = e0 + e1 + e2 + e3;
                float num = fmaf(m0, e0, fmaf(m1, e1, fmaf(m2, e2, m3 * e3)));
                float a = __fdividef(num, den);
                if (jj >= H) a = 0.f;
                unsigned hbb = f2bf_bits(a);
                unsigned lbb = lo_bits(a, hbb);
                unsigned short* rowp = (unsigned short*)(agg + node * AR32);
                int c = jj >> 3, o = jj & 7;
                rowp[c * 16 + o] = (unsigned short)hbb;
                rowp[c * 16 + 8 + o] = (unsigned short)lbb;
            }
        }
        __syncthreads();

        // ---- phase 2: C[32][200] = agg @ W (split-3 MFMA), epilogue into h_s ----
        floatx4 acc2[2][4];
#pragma unroll
        for (int mt = 0; mt < 2; mt++)
#pragma unroll
            for (int i = 0; i < 4; i++) acc2[mt][i] = (floatx4){0.f, 0.f, 0.f, 0.f};

        const unsigned short* WH = WtHi + (size_t)l * NP * KP;
        const unsigned short* WL = WtLo + (size_t)l * NP * KP;
        for (int ks = 0; ks < KP / 32; ks++) {
            short8 ah[2], al[2];
#pragma unroll
            for (int mt = 0; mt < 2; mt++) {
                int off = (16 * mt + l15) * AR32 + (4 * ks + quad) * 8;
                ah[mt] = *(const short8*)&agg[off];
                al[mt] = *(const short8*)&agg[off + 4];
            }
#pragma unroll 4
            for (int i = 0; i < ntcnt; i++) {
                int nt = wave + 4 * i;
                size_t boff = (size_t)(16 * nt + l15) * KP + ks * 32 + quad * 8;
                short8 vbh = *(const short8*)&WH[boff];
                short8 vbl = *(const short8*)&WL[boff];
#pragma unroll
                for (int mt = 0; mt < 2; mt++) {
                    acc2[mt][i] = __builtin_amdgcn_mfma_f32_16x16x32_bf16(ah[mt], vbh, acc2[mt][i], 0, 0, 0);
                    acc2[mt][i] = __builtin_amdgcn_mfma_f32_16x16x32_bf16(al[mt], vbh, acc2[mt][i], 0, 0, 0);
                    acc2[mt][i] = __builtin_amdgcn_mfma_f32_16x16x32_bf16(ah[mt], vbl, acc2[mt][i], 0, 0, 0);
                }
            }
        }
        for (int i = 0; i < ntcnt; i++) {
            int nt = wave + 4 * i, jj = nt * 16 + l15;
            if (jj < H) {
                float bj = gnn_b[l * H + jj];
#pragma unroll
                for (int mt = 0; mt < 2; mt++) {
#pragma unroll
                    for (int r = 0; r < 4; r++) {
                        float v = acc2[mt][i][r] + bj;
                        v = v > 0.f ? v : 0.f;
                        h_s[(16 * mt + quad * 4 + r) * HS + jj] += v;
                    }
                }
            }
        }
        __syncthreads();
    }

    // ---- write h + gf ----
    {
        float4* dst = (float4*)(h_out + (size_t)nbase * H);
        const float4* srcp = (const float4*)h_s;
        for (int p = tid; p < NPG * H / 4; p += 256) dst[p] = srcp[p];
    }
    if (tid < H) {
        float s = 0.f;
        for (int n = 0; n < NPG; n++) s += h_s[n * HS + tid];
        gf_out[g * H + tid] = s;
    }
}

// ---------------- readout attention ----------------
__global__ __launch_bounds__(256) void k_attn(const float* __restrict__ h,
                                              const float* __restrict__ gf,
                                              const float* __restrict__ lgW,
                                              const float* __restrict__ lgb,
                                              const float* __restrict__ prW,
                                              const float* __restrict__ prb,
                                              float* __restrict__ ctx_out) {
    __shared__ float h_s[NPG][H];
    __shared__ float gf_s[H];
    __shared__ float zp[256];
    __shared__ float z_s[NPG];
    __shared__ float a_s[NPG];
    __shared__ float wh_s[H];
    const int g = blockIdx.x, tid = threadIdx.x;

    for (int p = tid; p < NPG * H; p += 256) h_s[0][p] = h[g * NPG * H + p];
    if (tid < H) gf_s[tid] = gf[g * H + tid];
    __syncthreads();

    float c = 0.f;
    for (int jj = 0; jj < H; jj++) c = fmaf(fmaxf(gf_s[jj], 0.f), lgW[jj], c);

    {
        const int n = tid >> 3, l = tid & 7;
        float p = 0.f;
        for (int jj = l; jj < H; jj += 8) p = fmaf(h_s[n][jj], lgW[H + jj], p);
        zp[tid] = p;
    }
    __syncthreads();
    if (tid < NPG) {
        float z = c + lgb[0];
        for (int q = 0; q < 8; q++) z += zp[tid * 8 + q];
        z_s[tid] = z > 0.f ? z : 0.01f * z;
    }
    __syncthreads();
    float zmax = -1e30f;
    for (int n = 0; n < NPG; n++) zmax = fmaxf(zmax, z_s[n]);
    if (tid < NPG) a_s[tid] = __expf(z_s[tid] - zmax);
    __syncthreads();
    float den = 0.f;
    for (int n = 0; n < NPG; n++) den += a_s[n];

    if (tid < H) {
        float s = 0.f;
        for (int n = 0; n < NPG; n++) s = fmaf(a_s[n], h_s[n][tid], s);
        wh_s[tid] = s / den;
    }
    __syncthreads();

    if (tid < H) {
        float s = prb[tid];
        for (int i = 0; i < H; i++) s = fmaf(wh_s[i], prW[i * H + tid], s);
        ctx_out[g * H + tid] = s > 0.f ? s : __expf(s) - 1.f;
    }
}

// ---------------- GRU cell ----------------
#define GPB 8
#define GP 9
__global__ __launch_bounds__(256) void k_gru(const float* __restrict__ ctx,
                                             const float* __restrict__ gf,
                                             const float* __restrict__ Wih,
                                             const float* __restrict__ Whh,
                                             const float* __restrict__ bih,
                                             const float* __restrict__ bhh,
                                             float* __restrict__ gf_out) {
    __shared__ float ctx_s[GPB][H];
    __shared__ float gfs[GPB][H];
    __shared__ float gi_s[3 * H][GP];
    __shared__ float gh_s[3 * H][GP];
    const int gbase = blockIdx.x * GPB, tid = threadIdx.x;

    for (int p = tid; p < GPB * H; p += 256) {
        ctx_s[0][p] = ctx[gbase * H + p];
        gfs[0][p] = gf[gbase * H + p];
    }
    __syncthreads();

    for (int k = tid; k < 3 * H; k += 256) {
        float ai[GPB], ah[GPB];
        float bi = bih[k], bh = bhh[k];
#pragma unroll
        for (int q = 0; q < GPB; q++) { ai[q] = bi; ah[q] = bh; }
        for (int jj = 0; jj < H; jj++) {
            float wi = Wih[k * H + jj];
            float wh = Whh[k * H + jj];
#pragma unroll
            for (int q = 0; q < GPB; q++) {
                ai[q] = fmaf(ctx_s[q][jj], wi, ai[q]);
                ah[q] = fmaf(gfs[q][jj], wh, ah[q]);
            }
        }
#pragma unroll
        for (int q = 0; q < GPB; q++) { gi_s[k][q] = ai[q]; gh_s[k][q] = ah[q]; }
    }
    __syncthreads();

    for (int p = tid; p < GPB * H; p += 256) {
        int q = p / H, jj = p - q * H;
        float r = sigmoidf_(gi_s[jj][q] + gh_s[jj][q]);
        float u = sigmoidf_(gi_s[H + jj][q] + gh_s[H + jj][q]);
        float nn = tanhf(gi_s[2 * H + jj][q] + r * gh_s[2 * H + jj][q]);
        gf_out[(gbase + q) * H + jj] = (1.f - u) * nn + u * gfs[q][jj];
    }
}

extern "C" void kernel_launch(void* const* d_in, const int* in_sizes, int n_in,
                              void* d_out, int out_size, void* d_ws, size_t ws_size,
                              hipStream_t stream) {
    const float* node_feat = (const float*)d_in[0];
    const float* edge_feat = (const float*)d_in[1];
    const int* src = (const int*)d_in[2];
    const float* node_W = (const float*)d_in[5];
    const float* node_b = (const float*)d_in[6];
    const float* edge_W = (const float*)d_in[7];
    const float* edge_b = (const float*)d_in[8];
    const float* gnn_W = (const float*)d_in[9];
    const float* gnn_b = (const float*)d_in[10];
    const float* lg_W = (const float*)d_in[11];
    const float* lg_b = (const float*)d_in[12];
    const float* pr_W = (const float*)d_in[13];
    const float* pr_b = (const float*)d_in[14];
    const float* W_ih = (const float*)d_in[15];
    const float* W_hh = (const float*)d_in[16];
    const float* b_ih = (const float*)d_in[17];
    const float* b_hh = (const float*)d_in[18];
    float* out = (float*)d_out;

    char* ws = (char*)d_ws;
    size_t off = 0;
    auto alloc = [&](size_t bytes) { void* p = ws + off; off += (bytes + 4095) & ~(size_t)4095; return p; };
    float* h = (float*)alloc((size_t)V * H * 4);
    unsigned short* Anf = (unsigned short*)alloc((size_t)V * NFS * 2);
    unsigned short* Aedge = (unsigned short*)alloc((size_t)NE * EK * 2);
    unsigned short* WtHi = (unsigned short*)alloc((size_t)NL * NP * KP * 2);
    unsigned short* WtLo = (unsigned short*)alloc((size_t)NL * NP * KP * 2);
    unsigned short* BnW = (unsigned short*)alloc((size_t)NP * 192 * 2);
    unsigned short* eWp = (unsigned short*)alloc((size_t)NP * 64 * 2);
    float* gf_ws = (float*)alloc((size_t)G * H * 4);
    float* ctx_ws = (float*)alloc((size_t)G * H * 4);

    k_prep_w<<<(NL * NP * KP + 255) / 256, 256, 0, stream>>>(gnn_W, WtHi, WtLo);
    k_prep_ew<<<1, 256, 0, stream>>>(edge_W, edge_b, eWp);
    k_prep_ef<<<NE / 256, 256, 0, stream>>>(edge_feat, Aedge);
    k_prep_nf<<<V / 64, 256, 0, stream>>>(node_feat, (unsigned int*)Anf);
    k_prep_nw<<<(NP * 96 + 255) / 256, 256, 0, stream>>>(node_W, node_b, (unsigned int*)BnW);

    k_mega<<<G, 256, 0, stream>>>(Anf, BnW, Aedge, eWp, src, WtHi, WtLo, gnn_b, h, gf_ws);

    for (int t = 0; t < 2; t++) {
        k_attn<<<G, 256, 0, stream>>>(h, gf_ws, lg_W + (size_t)t * 2 * H, lg_b + t,
                                      pr_W + (size_t)t * H * H, pr_b + (size_t)t * H, ctx_ws);
        float* gout = (t == 1) ? out : gf_ws;
        k_gru<<<G / GPB, 256, 0, stream>>>(ctx_ws, gf_ws, W_ih + (size_t)t * 3 * H * H,
                                           W_hh + (size_t)t * 3 * H * H, b_ih + (size_t)t * 3 * H,
                                           b_hh + (size_t)t * 3 * H, gout);
    }
}